// Round 5
// baseline (775.001 us; speedup 1.0000x reference)
//
#include <hip/hip_runtime.h>
#include <stdint.h>

#define LOG_B 17
#define NB (1u << LOG_B)
#define FINE_NODES 512
#define CSHIFT 13            // coarse bucket = 8192 nodes = 16 fine buckets
#define EPB 16384

__host__ __device__ constexpr uint32_t cmix(uint32_t v, uint32_t c1, uint32_t c2) {
    v = (v ^ (v >> 16)) * c1;
    v = (v ^ (v >> 13)) * c2;
    return v ^ (v >> 16);
}

__device__ __forceinline__ uint32_t mixh(uint32_t v, uint32_t c1, uint32_t c2) {
    v = (v ^ (v >> 16)) * c1;
    v = (v ^ (v >> 13)) * c2;
    return v ^ (v >> 16);
}

struct Luts { uint32_t ha[64]; uint32_t hb[64]; };
constexpr Luts make_luts() {
    Luts l{};
    for (uint32_t i = 0; i < 64; i++) {
        l.ha[i] = cmix(i, 0x045D9F3Bu, 0x045D9F3Bu);
        l.hb[i] = cmix(i, 0x9E3779B1u, 0x85EBCA77u);
    }
    return l;
}
__constant__ Luts LUT = make_luts();

// ---- P1: coarse bin (62 buckets -> ~264-record runs, full cache lines).
// Two planes: u16 fine-record, u8 fine-id-within-coarse. ----
__global__ __launch_bounds__(256) void k_bin(const int* __restrict__ row, const int* __restrict__ col,
                                             const int* __restrict__ x, uint16_t* __restrict__ b16,
                                             uint8_t* __restrict__ b8, uint32_t* __restrict__ cursor,
                                             int E, int cap) {
    __shared__ uint32_t hist[64];
    __shared__ uint32_t gbase[64];
    int t = threadIdx.x;
    int base = blockIdx.x * EPB;
    int nend = min(E - base, EPB);
    if (t < 64) hist[t] = 0;
    __syncthreads();

    const int4* col4 = (const int4*)(col + base);
    const int4* row4 = (const int4*)(row + base);
    int n4 = nend >> 2;

    for (int k = t; k < n4; k += 256) {
        int4 c = col4[k];
        atomicAdd(&hist[(uint32_t)c.x >> CSHIFT], 1u);
        atomicAdd(&hist[(uint32_t)c.y >> CSHIFT], 1u);
        atomicAdd(&hist[(uint32_t)c.z >> CSHIFT], 1u);
        atomicAdd(&hist[(uint32_t)c.w >> CSHIFT], 1u);
    }
    for (int k = (n4 << 2) + t; k < nend; k += 256)
        atomicAdd(&hist[(uint32_t)col[base + k] >> CSHIFT], 1u);
    __syncthreads();

    if (t < 64) {
        uint32_t h = hist[t];
        gbase[t] = h ? atomicAdd(&cursor[t], h) : 0u;
        hist[t] = 0;
    }
    __syncthreads();

    for (int k = t; k < n4; k += 256) {
        int4 c = col4[k];
        int4 r = row4[k];
        {
            uint32_t d = (uint32_t)c.x, cb = d >> CSHIFT;
            uint32_t pos = cb * (uint32_t)cap + gbase[cb] + atomicAdd(&hist[cb], 1u);
            b16[pos] = (uint16_t)(((d & 511u) << 6) | (uint32_t)x[r.x]);
            b8[pos] = (uint8_t)((d >> 9) & 15u);
        }
        {
            uint32_t d = (uint32_t)c.y, cb = d >> CSHIFT;
            uint32_t pos = cb * (uint32_t)cap + gbase[cb] + atomicAdd(&hist[cb], 1u);
            b16[pos] = (uint16_t)(((d & 511u) << 6) | (uint32_t)x[r.y]);
            b8[pos] = (uint8_t)((d >> 9) & 15u);
        }
        {
            uint32_t d = (uint32_t)c.z, cb = d >> CSHIFT;
            uint32_t pos = cb * (uint32_t)cap + gbase[cb] + atomicAdd(&hist[cb], 1u);
            b16[pos] = (uint16_t)(((d & 511u) << 6) | (uint32_t)x[r.z]);
            b8[pos] = (uint8_t)((d >> 9) & 15u);
        }
        {
            uint32_t d = (uint32_t)c.w, cb = d >> CSHIFT;
            uint32_t pos = cb * (uint32_t)cap + gbase[cb] + atomicAdd(&hist[cb], 1u);
            b16[pos] = (uint16_t)(((d & 511u) << 6) | (uint32_t)x[r.w]);
            b8[pos] = (uint8_t)((d >> 9) & 15u);
        }
    }
    for (int k = (n4 << 2) + t; k < nend; k += 256) {
        int i = base + k;
        uint32_t d = (uint32_t)col[i], cb = d >> CSHIFT;
        uint32_t pos = cb * (uint32_t)cap + gbase[cb] + atomicAdd(&hist[cb], 1u);
        b16[pos] = (uint16_t)(((d & 511u) << 6) | (uint32_t)x[row[i]]);
        b8[pos] = (uint8_t)((d >> 9) & 15u);
    }
}

// ---- P2+P3 merged: one block per fine bucket; stream coarse planes, filter
// fine-id, LDS color histogram, then fused signature computation. ----
__global__ __launch_bounds__(256) void k_accsig(const uint16_t* __restrict__ b16,
                                                const uint8_t* __restrict__ b8,
                                                const uint32_t* __restrict__ cursor,
                                                const int* __restrict__ x,
                                                unsigned long long* __restrict__ sigs,
                                                uint32_t* __restrict__ bcnt, int N, int cap) {
    __shared__ uint32_t cnt[FINE_NODES * 32];  // 64 KB: u16-pair counters, 64 colors/node
    int t = threadIdx.x;
    int fb = blockIdx.x;
    int cb = fb >> 4;
    uint32_t f = (uint32_t)(fb & 15);
    for (int i = t; i < FINE_NODES * 32; i += 256) cnt[i] = 0;
    __syncthreads();

    uint32_t m = cursor[cb];
    const uint16_t* p16 = b16 + (size_t)cb * (uint32_t)cap;
    const uint8_t* p8 = b8 + (size_t)cb * (uint32_t)cap;
    const uint32_t* p8v = (const uint32_t*)p8;
    const uint2* p16v = (const uint2*)p16;
    uint32_t m4 = m >> 2;
    for (uint32_t k = t; k < m4; k += 256) {
        uint32_t fids = p8v[k];
        uint2 rv = p16v[k];
        if ((fids & 255u) == f) {
            uint32_t rec = rv.x & 0xFFFFu, n = rec >> 6, c = rec & 63u;
            atomicAdd(&cnt[n * 32 + (c >> 1)], 1u << (16u * (c & 1u)));
        }
        if (((fids >> 8) & 255u) == f) {
            uint32_t rec = rv.x >> 16, n = rec >> 6, c = rec & 63u;
            atomicAdd(&cnt[n * 32 + (c >> 1)], 1u << (16u * (c & 1u)));
        }
        if (((fids >> 16) & 255u) == f) {
            uint32_t rec = rv.y & 0xFFFFu, n = rec >> 6, c = rec & 63u;
            atomicAdd(&cnt[n * 32 + (c >> 1)], 1u << (16u * (c & 1u)));
        }
        if (((fids >> 24) & 255u) == f) {
            uint32_t rec = rv.y >> 16, n = rec >> 6, c = rec & 63u;
            atomicAdd(&cnt[n * 32 + (c >> 1)], 1u << (16u * (c & 1u)));
        }
    }
    for (uint32_t k = (m4 << 2) + t; k < m; k += 256) {
        if ((uint32_t)p8[k] == f) {
            uint32_t rec = p16[k], n = rec >> 6, c = rec & 63u;
            atomicAdd(&cnt[n * 32 + (c >> 1)], 1u << (16u * (c & 1u)));
        }
    }
    __syncthreads();

    for (int n = t; n < FINE_NODES; n += 256) {
        int g = fb * FINE_NODES + n;
        if (g >= N) break;
        uint32_t sum_a = 0, sum_b = 0;
#pragma unroll
        for (int w = 0; w < 32; w++) {
            uint32_t wp = (uint32_t)(w + n) & 31u;   // skew: conflict-free LDS banks
            uint32_t v = cnt[n * 32 + wp];
            uint32_t lo = v & 0xFFFFu, hi = v >> 16;
            sum_a += lo * LUT.ha[2 * wp] + hi * LUT.ha[2 * wp + 1];
            sum_b += lo * LUT.hb[2 * wp] + hi * LUT.hb[2 * wp + 1];
        }
        uint32_t xv = (uint32_t)x[g];
        uint32_t ha = LUT.ha[xv];
        uint32_t hb = LUT.hb[xv];
        uint32_t sa = mixh(ha * 0x27D4EB2Fu + sum_a, 0xC2B2AE3Du, 0x165667B1u);
        uint32_t sb = mixh(hb * 0x61C88647u + sum_b, 0x045D9F3Bu, 0x27D4EB2Fu);
        unsigned long long key = ((unsigned long long)sa << 32) | (unsigned long long)sb;
        sigs[g] = key;
        atomicAdd(&bcnt[(uint32_t)(key >> (64 - LOG_B))], 1u);
    }
}

// ---- exclusive scan over NB uint32 (3-kernel hierarchical) ----
__global__ void k_scan1(const uint32_t* __restrict__ in, uint32_t* __restrict__ out,
                        uint32_t* __restrict__ part) {
    __shared__ uint32_t s[1024];
    int t = threadIdx.x;
    int idx = blockIdx.x * 1024 + t;
    uint32_t v = in[idx];
    s[t] = v;
    __syncthreads();
    for (int off = 1; off < 1024; off <<= 1) {
        uint32_t add = (t >= off) ? s[t - off] : 0u;
        __syncthreads();
        s[t] += add;
        __syncthreads();
    }
    out[idx] = s[t] - v;                 // exclusive
    if (t == 1023) part[blockIdx.x] = s[t];
}

__global__ void k_scan2(uint32_t* __restrict__ part) {  // 256 entries (zero-initialized)
    __shared__ uint32_t s[256];
    int t = threadIdx.x;
    uint32_t v = part[t];
    s[t] = v;
    __syncthreads();
    for (int off = 1; off < 256; off <<= 1) {
        uint32_t add = (t >= off) ? s[t - off] : 0u;
        __syncthreads();
        s[t] += add;
        __syncthreads();
    }
    part[t] = s[t] - v;                  // exclusive
}

__global__ void k_scan3(uint32_t* __restrict__ out, const uint32_t* __restrict__ part) {
    int idx = blockIdx.x * 1024 + threadIdx.x;
    out[idx] += part[blockIdx.x];
}

// ---- scatter keys into sort buckets ----
__global__ void k_scatter(const unsigned long long* __restrict__ sigs,
                          const uint32_t* __restrict__ boff, uint32_t* __restrict__ bcur,
                          unsigned long long* __restrict__ skey, uint32_t* __restrict__ snode,
                          int N) {
    int i = blockIdx.x * blockDim.x + threadIdx.x;
    if (i >= N) return;
    unsigned long long key = sigs[i];
    uint32_t b = (uint32_t)(key >> (64 - LOG_B));
    uint32_t pos = boff[b] + atomicAdd(&bcur[b], 1u);
    skey[pos] = key;
    snode[pos] = (uint32_t)i;
}

// ---- per-bucket insertion sort, distinct counts ----
__global__ void k_bsort(unsigned long long* __restrict__ skey, uint32_t* __restrict__ snode,
                        const uint32_t* __restrict__ boff, uint32_t* __restrict__ ldx,
                        uint32_t* __restrict__ dcnt, int N) {
    int b = blockIdx.x * blockDim.x + threadIdx.x;
    if (b >= (int)NB) return;
    uint32_t s0 = boff[b];
    uint32_t s1 = (b == (int)NB - 1) ? (uint32_t)N : boff[b + 1];
    for (uint32_t i = s0 + 1; i < s1; i++) {
        unsigned long long k = skey[i];
        uint32_t nd = snode[i];
        uint32_t j = i;
        while (j > s0 && skey[j - 1] > k) {
            skey[j] = skey[j - 1];
            snode[j] = snode[j - 1];
            j--;
        }
        skey[j] = k;
        snode[j] = nd;
    }
    uint32_t d = 0;
    unsigned long long prev = 0ull;
    for (uint32_t i = s0; i < s1; i++) {
        unsigned long long k = skey[i];
        if (i == s0 || k != prev) d++;
        prev = k;
        ldx[i] = d - 1;
    }
    dcnt[b] = d;
}

// ---- final label write ----
__global__ void k_out(const unsigned long long* __restrict__ skey,
                      const uint32_t* __restrict__ snode, const uint32_t* __restrict__ ldx,
                      const uint32_t* __restrict__ doff, int* __restrict__ out, int N) {
    int i = blockIdx.x * blockDim.x + threadIdx.x;
    if (i >= N) return;
    unsigned long long key = skey[i];
    uint32_t b = (uint32_t)(key >> (64 - LOG_B));
    out[snode[i]] = (int)(doff[b] + ldx[i]);
}

extern "C" void kernel_launch(void* const* d_in, const int* in_sizes, int n_in,
                              void* d_out, int out_size, void* d_ws, size_t ws_size,
                              hipStream_t stream) {
    const int* x = (const int*)d_in[0];
    const int* ei = (const int*)d_in[1];
    int N = in_sizes[0];
    int E = in_sizes[1] / 2;
    const int* row = ei;
    const int* col = ei + E;

    int nfine = (N + FINE_NODES - 1) / FINE_NODES;       // 977
    long mean = ((long)E << CSHIFT) / N;                 // expected records per full coarse bucket
    long capl = mean + mean / 64 + 2048;                 // ~12 sigma margin
    int cap = (int)((capl + 255) & ~255L);               // 256-aligned (vector reads)

    char* p = (char*)d_ws;
    auto alloc = [&](size_t bytes) -> char* {
        char* r = p;
        p += (bytes + 255) & ~(size_t)255;
        return r;
    };
    // zero-needing region first (single memsetAsync)
    uint32_t* cursor = (uint32_t*)alloc(64 * 4);
    uint32_t* bcnt   = (uint32_t*)alloc((size_t)NB * 4);
    uint32_t* bcur   = (uint32_t*)alloc((size_t)NB * 4);
    uint32_t* dcnt   = (uint32_t*)alloc((size_t)NB * 4);
    uint32_t* part   = (uint32_t*)alloc(256 * 4);
    size_t zbytes = (size_t)(p - (char*)d_ws);
    unsigned long long* sigs = (unsigned long long*)alloc((size_t)N * 8);
    uint16_t* b16 = (uint16_t*)alloc((size_t)64 * cap * 2);
    uint8_t*  b8  = (uint8_t*)alloc((size_t)64 * cap);
    // post-P2 aliases inside the (then-dead) b16 plane region:
    char* q = (char*)b16;
    auto alias = [&](size_t bytes) -> char* {
        char* r = q;
        q += (bytes + 255) & ~(size_t)255;
        return r;
    };
    unsigned long long* skey = (unsigned long long*)alias((size_t)N * 8);
    uint32_t* snode = (uint32_t*)alias((size_t)N * 4);
    uint32_t* ldx   = (uint32_t*)alias((size_t)N * 4);
    uint32_t* boff  = (uint32_t*)alias((size_t)NB * 4);
    uint32_t* doff  = (uint32_t*)alias((size_t)NB * 4);

    hipMemsetAsync(d_ws, 0, zbytes, stream);

    int nbN = (N + 255) / 256;
    int nbBin = (E + EPB - 1) / EPB;

    k_bin<<<nbBin, 256, 0, stream>>>(row, col, x, b16, b8, cursor, E, cap);
    k_accsig<<<nfine, 256, 0, stream>>>(b16, b8, cursor, x, sigs, bcnt, N, cap);

    k_scan1<<<NB / 1024, 1024, 0, stream>>>(bcnt, boff, part);
    k_scan2<<<1, 256, 0, stream>>>(part);
    k_scan3<<<NB / 1024, 1024, 0, stream>>>(boff, part);

    k_scatter<<<nbN, 256, 0, stream>>>(sigs, boff, bcur, skey, snode, N);
    k_bsort<<<NB / 256, 256, 0, stream>>>(skey, snode, boff, ldx, dcnt, N);

    k_scan1<<<NB / 1024, 1024, 0, stream>>>(dcnt, doff, part);
    k_scan2<<<1, 256, 0, stream>>>(part);
    k_scan3<<<NB / 1024, 1024, 0, stream>>>(doff, part);

    k_out<<<nbN, 256, 0, stream>>>(skey, snode, ldx, doff, (int*)d_out, N);
}

// Round 6
// 523.964 us; speedup vs baseline: 1.4791x; 1.4791x over previous
//
#include <hip/hip_runtime.h>
#include <stdint.h>

#define LOG_B 17
#define NB (1u << LOG_B)
#define FINE_NODES 512
#define NBKT 1024            // >= ceil(N/512) = 977, padded to pow2 for scans
#define EPB 16384

__host__ __device__ constexpr uint32_t cmix(uint32_t v, uint32_t c1, uint32_t c2) {
    v = (v ^ (v >> 16)) * c1;
    v = (v ^ (v >> 13)) * c2;
    return v ^ (v >> 16);
}

__device__ __forceinline__ uint32_t mixh(uint32_t v, uint32_t c1, uint32_t c2) {
    v = (v ^ (v >> 16)) * c1;
    v = (v ^ (v >> 13)) * c2;
    return v ^ (v >> 16);
}

struct Luts { uint32_t ha[64]; uint32_t hb[64]; };
constexpr Luts make_luts() {
    Luts l{};
    for (uint32_t i = 0; i < 64; i++) {
        l.ha[i] = cmix(i, 0x045D9F3Bu, 0x045D9F3Bu);
        l.hb[i] = cmix(i, 0x9E3779B1u, 0x85EBCA77u);
    }
    return l;
}
__constant__ Luts LUT = make_luts();

// ---- P1: bin edges by fine (512-node) bucket, staged wholly in LDS, then
// burst-copied out so every destination cache line is written once, fully. ----
__global__ __launch_bounds__(256) void k_bin(const int* __restrict__ row, const int* __restrict__ col,
                                             const int* __restrict__ x, uint16_t* __restrict__ bins,
                                             uint32_t* __restrict__ cursor, int E, int nbkt, int cap) {
    __shared__ uint16_t stage[EPB];       // 32 KB
    __shared__ uint32_t hist[NBKT];       // 4 KB
    __shared__ uint32_t start[NBKT];      // 4 KB
    __shared__ uint32_t gbase[NBKT];      // 4 KB
    __shared__ uint32_t tmp[256];
    int t = threadIdx.x;
    int base = blockIdx.x * EPB;
    int nend = min(E - base, EPB);
    for (int b = t; b < NBKT; b += 256) hist[b] = 0;
    __syncthreads();

    const int4* col4 = (const int4*)(col + base);
    const int4* row4 = (const int4*)(row + base);
    int n4 = nend >> 2;

    // pass 1: count
    for (int k = t; k < n4; k += 256) {
        int4 c = col4[k];
        atomicAdd(&hist[(uint32_t)c.x >> 9], 1u);
        atomicAdd(&hist[(uint32_t)c.y >> 9], 1u);
        atomicAdd(&hist[(uint32_t)c.z >> 9], 1u);
        atomicAdd(&hist[(uint32_t)c.w >> 9], 1u);
    }
    for (int k = (n4 << 2) + t; k < nend; k += 256)
        atomicAdd(&hist[(uint32_t)col[base + k] >> 9], 1u);
    __syncthreads();

    // exclusive scan of hist[0..1023] -> start[], 4 chunks of 256 with carry
    uint32_t carry = 0;
#pragma unroll
    for (int c = 0; c < 4; c++) {
        uint32_t v = hist[c * 256 + t];
        tmp[t] = v;
        __syncthreads();
        for (int off = 1; off < 256; off <<= 1) {
            uint32_t add = (t >= off) ? tmp[t - off] : 0u;
            __syncthreads();
            tmp[t] += add;
            __syncthreads();
        }
        start[c * 256 + t] = tmp[t] - v + carry;
        carry += tmp[255];
        __syncthreads();
    }

    // reserve global runs; zero hist for reuse as scatter offsets
    for (int b = t; b < nbkt; b += 256) {
        uint32_t h = hist[b];
        gbase[b] = h ? atomicAdd(&cursor[b], h) : 0u;
        hist[b] = 0;
    }
    __syncthreads();

    // pass 2: scatter records into LDS staging
    for (int k = t; k < n4; k += 256) {
        int4 c = col4[k];
        int4 r = row4[k];
        {
            uint32_t d = (uint32_t)c.x, b = d >> 9;
            uint32_t p = start[b] + atomicAdd(&hist[b], 1u);
            stage[p] = (uint16_t)(((d & 511u) << 6) | (uint32_t)x[r.x]);
        }
        {
            uint32_t d = (uint32_t)c.y, b = d >> 9;
            uint32_t p = start[b] + atomicAdd(&hist[b], 1u);
            stage[p] = (uint16_t)(((d & 511u) << 6) | (uint32_t)x[r.y]);
        }
        {
            uint32_t d = (uint32_t)c.z, b = d >> 9;
            uint32_t p = start[b] + atomicAdd(&hist[b], 1u);
            stage[p] = (uint16_t)(((d & 511u) << 6) | (uint32_t)x[r.z]);
        }
        {
            uint32_t d = (uint32_t)c.w, b = d >> 9;
            uint32_t p = start[b] + atomicAdd(&hist[b], 1u);
            stage[p] = (uint16_t)(((d & 511u) << 6) | (uint32_t)x[r.w]);
        }
    }
    for (int k = (n4 << 2) + t; k < nend; k += 256) {
        int i = base + k;
        uint32_t d = (uint32_t)col[i], b = d >> 9;
        uint32_t p = start[b] + atomicAdd(&hist[b], 1u);
        stage[p] = (uint16_t)(((d & 511u) << 6) | (uint32_t)x[row[i]]);
    }
    __syncthreads();

    // pass 3: burst copy-out, one wave per bucket round-robin; contiguous
    // u16 stores -> each line written once, back-to-back.
    int wid = t >> 6, lane = t & 63;
    for (int b = wid; b < nbkt; b += 4) {
        uint32_t cnt = hist[b];
        if (!cnt) continue;
        uint32_t s0 = start[b];
        uint16_t* dst = bins + (size_t)b * (uint32_t)cap + gbase[b];
        for (uint32_t off = lane; off < cnt; off += 64)
            dst[off] = stage[s0 + off];
    }
}

// ---- P2: per-bucket color histogram in LDS + fused signature computation ----
__global__ __launch_bounds__(256) void k_accsig(const uint16_t* __restrict__ bins,
                                                const uint32_t* __restrict__ cursor,
                                                const int* __restrict__ x,
                                                unsigned long long* __restrict__ sigs,
                                                uint32_t* __restrict__ bcnt, int N, int cap) {
    __shared__ uint32_t cnt[FINE_NODES * 32];  // 64 KB: u16-pair counters, 64 colors/node
    int t = threadIdx.x;
    int b = blockIdx.x;
    for (int i = t; i < FINE_NODES * 32; i += 256) cnt[i] = 0;
    __syncthreads();
    uint32_t m = cursor[b];
    const uint16_t* mybins = bins + (size_t)b * (uint32_t)cap;
    const uint2* p16v = (const uint2*)mybins;   // cap % 4 == 0 -> 8B aligned
    uint32_t m4 = m >> 2;
    for (uint32_t k = t; k < m4; k += 256) {
        uint2 rv = p16v[k];
        {
            uint32_t rec = rv.x & 0xFFFFu, n = rec >> 6, c = rec & 63u;
            atomicAdd(&cnt[n * 32 + (c >> 1)], 1u << (16u * (c & 1u)));
        }
        {
            uint32_t rec = rv.x >> 16, n = rec >> 6, c = rec & 63u;
            atomicAdd(&cnt[n * 32 + (c >> 1)], 1u << (16u * (c & 1u)));
        }
        {
            uint32_t rec = rv.y & 0xFFFFu, n = rec >> 6, c = rec & 63u;
            atomicAdd(&cnt[n * 32 + (c >> 1)], 1u << (16u * (c & 1u)));
        }
        {
            uint32_t rec = rv.y >> 16, n = rec >> 6, c = rec & 63u;
            atomicAdd(&cnt[n * 32 + (c >> 1)], 1u << (16u * (c & 1u)));
        }
    }
    for (uint32_t k = (m4 << 2) + t; k < m; k += 256) {
        uint32_t rec = mybins[k], n = rec >> 6, c = rec & 63u;
        atomicAdd(&cnt[n * 32 + (c >> 1)], 1u << (16u * (c & 1u)));
    }
    __syncthreads();

    for (int n = t; n < FINE_NODES; n += 256) {
        int g = b * FINE_NODES + n;
        if (g >= N) break;
        uint32_t sum_a = 0, sum_b = 0;
#pragma unroll
        for (int w = 0; w < 32; w++) {
            uint32_t wp = (uint32_t)(w + n) & 31u;   // skew: conflict-free LDS banks
            uint32_t v = cnt[n * 32 + wp];
            uint32_t lo = v & 0xFFFFu, hi = v >> 16;
            sum_a += lo * LUT.ha[2 * wp] + hi * LUT.ha[2 * wp + 1];
            sum_b += lo * LUT.hb[2 * wp] + hi * LUT.hb[2 * wp + 1];
        }
        uint32_t xv = (uint32_t)x[g];
        uint32_t ha = LUT.ha[xv];
        uint32_t hb = LUT.hb[xv];
        uint32_t sa = mixh(ha * 0x27D4EB2Fu + sum_a, 0xC2B2AE3Du, 0x165667B1u);
        uint32_t sb = mixh(hb * 0x61C88647u + sum_b, 0x045D9F3Bu, 0x27D4EB2Fu);
        unsigned long long key = ((unsigned long long)sa << 32) | (unsigned long long)sb;
        sigs[g] = key;
        atomicAdd(&bcnt[(uint32_t)(key >> (64 - LOG_B))], 1u);
    }
}

// ---- exclusive scan over NB uint32 (3-kernel hierarchical) ----
__global__ void k_scan1(const uint32_t* __restrict__ in, uint32_t* __restrict__ out,
                        uint32_t* __restrict__ part) {
    __shared__ uint32_t s[1024];
    int t = threadIdx.x;
    int idx = blockIdx.x * 1024 + t;
    uint32_t v = in[idx];
    s[t] = v;
    __syncthreads();
    for (int off = 1; off < 1024; off <<= 1) {
        uint32_t add = (t >= off) ? s[t - off] : 0u;
        __syncthreads();
        s[t] += add;
        __syncthreads();
    }
    out[idx] = s[t] - v;                 // exclusive
    if (t == 1023) part[blockIdx.x] = s[t];
}

__global__ void k_scan2(uint32_t* __restrict__ part) {  // 256 entries (zero-padded)
    __shared__ uint32_t s[256];
    int t = threadIdx.x;
    uint32_t v = part[t];
    s[t] = v;
    __syncthreads();
    for (int off = 1; off < 256; off <<= 1) {
        uint32_t add = (t >= off) ? s[t - off] : 0u;
        __syncthreads();
        s[t] += add;
        __syncthreads();
    }
    part[t] = s[t] - v;                  // exclusive
}

__global__ void k_scan3(uint32_t* __restrict__ out, const uint32_t* __restrict__ part) {
    int idx = blockIdx.x * 1024 + threadIdx.x;
    out[idx] += part[blockIdx.x];
}

// ---- scatter keys into sort buckets ----
__global__ void k_scatter(const unsigned long long* __restrict__ sigs,
                          const uint32_t* __restrict__ boff, uint32_t* __restrict__ bcur,
                          unsigned long long* __restrict__ skey, uint32_t* __restrict__ snode,
                          int N) {
    int i = blockIdx.x * blockDim.x + threadIdx.x;
    if (i >= N) return;
    unsigned long long key = sigs[i];
    uint32_t b = (uint32_t)(key >> (64 - LOG_B));
    uint32_t pos = boff[b] + atomicAdd(&bcur[b], 1u);
    skey[pos] = key;
    snode[pos] = (uint32_t)i;
}

// ---- per-bucket insertion sort, distinct counts ----
__global__ void k_bsort(unsigned long long* __restrict__ skey, uint32_t* __restrict__ snode,
                        const uint32_t* __restrict__ boff, uint32_t* __restrict__ ldx,
                        uint32_t* __restrict__ dcnt, int N) {
    int b = blockIdx.x * blockDim.x + threadIdx.x;
    if (b >= (int)NB) return;
    uint32_t s0 = boff[b];
    uint32_t s1 = (b == (int)NB - 1) ? (uint32_t)N : boff[b + 1];
    for (uint32_t i = s0 + 1; i < s1; i++) {
        unsigned long long k = skey[i];
        uint32_t nd = snode[i];
        uint32_t j = i;
        while (j > s0 && skey[j - 1] > k) {
            skey[j] = skey[j - 1];
            snode[j] = snode[j - 1];
            j--;
        }
        skey[j] = k;
        snode[j] = nd;
    }
    uint32_t d = 0;
    unsigned long long prev = 0ull;
    for (uint32_t i = s0; i < s1; i++) {
        unsigned long long k = skey[i];
        if (i == s0 || k != prev) d++;
        prev = k;
        ldx[i] = d - 1;
    }
    dcnt[b] = d;
}

// ---- final label write ----
__global__ void k_out(const unsigned long long* __restrict__ skey,
                      const uint32_t* __restrict__ snode, const uint32_t* __restrict__ ldx,
                      const uint32_t* __restrict__ doff, int* __restrict__ out, int N) {
    int i = blockIdx.x * blockDim.x + threadIdx.x;
    if (i >= N) return;
    unsigned long long key = skey[i];
    uint32_t b = (uint32_t)(key >> (64 - LOG_B));
    out[snode[i]] = (int)(doff[b] + ldx[i]);
}

extern "C" void kernel_launch(void* const* d_in, const int* in_sizes, int n_in,
                              void* d_out, int out_size, void* d_ws, size_t ws_size,
                              hipStream_t stream) {
    const int* x = (const int*)d_in[0];
    const int* ei = (const int*)d_in[1];
    int N = in_sizes[0];
    int E = in_sizes[1] / 2;
    const int* row = ei;
    const int* col = ei + E;

    int nbkt = (N + FINE_NODES - 1) / FINE_NODES;        // 977
    int cap = E / nbkt + (E / nbkt) / 16 + 1024;         // mean + ~8 sigma margin
    cap = (cap + 3) & ~3;                                // 8B-aligned runs for uint2 loads

    char* p = (char*)d_ws;
    auto alloc = [&](size_t bytes) -> char* {
        char* r = p;
        p += (bytes + 255) & ~(size_t)255;
        return r;
    };
    // zero-needing region first (single memsetAsync)
    uint32_t* cursor = (uint32_t*)alloc((size_t)NBKT * 4);
    uint32_t* bcnt   = (uint32_t*)alloc((size_t)NB * 4);
    uint32_t* bcur   = (uint32_t*)alloc((size_t)NB * 4);
    uint32_t* dcnt   = (uint32_t*)alloc((size_t)NB * 4);
    uint32_t* part   = (uint32_t*)alloc(256 * 4);
    size_t zbytes = (size_t)(p - (char*)d_ws);
    unsigned long long* sigs = (unsigned long long*)alloc((size_t)N * 8);
    uint16_t* bins = (uint16_t*)alloc((size_t)nbkt * cap * 2);
    // post-accsig aliases inside the (then-dead) bins region:
    char* q = (char*)bins;
    auto alias = [&](size_t bytes) -> char* {
        char* r = q;
        q += (bytes + 255) & ~(size_t)255;
        return r;
    };
    unsigned long long* skey = (unsigned long long*)alias((size_t)N * 8);
    uint32_t* snode = (uint32_t*)alias((size_t)N * 4);
    uint32_t* ldx   = (uint32_t*)alias((size_t)N * 4);
    uint32_t* boff  = (uint32_t*)alias((size_t)NB * 4);
    uint32_t* doff  = (uint32_t*)alias((size_t)NB * 4);

    hipMemsetAsync(d_ws, 0, zbytes, stream);

    int nbN = (N + 255) / 256;
    int nbBin = (E + EPB - 1) / EPB;

    k_bin<<<nbBin, 256, 0, stream>>>(row, col, x, bins, cursor, E, nbkt, cap);
    k_accsig<<<nbkt, 256, 0, stream>>>(bins, cursor, x, sigs, bcnt, N, cap);

    k_scan1<<<NB / 1024, 1024, 0, stream>>>(bcnt, boff, part);
    k_scan2<<<1, 256, 0, stream>>>(part);
    k_scan3<<<NB / 1024, 1024, 0, stream>>>(boff, part);

    k_scatter<<<nbN, 256, 0, stream>>>(sigs, boff, bcur, skey, snode, N);
    k_bsort<<<NB / 256, 256, 0, stream>>>(skey, snode, boff, ldx, dcnt, N);

    k_scan1<<<NB / 1024, 1024, 0, stream>>>(dcnt, doff, part);
    k_scan2<<<1, 256, 0, stream>>>(part);
    k_scan3<<<NB / 1024, 1024, 0, stream>>>(doff, part);

    k_out<<<nbN, 256, 0, stream>>>(skey, snode, ldx, doff, (int*)d_out, N);
}